// Round 1
// baseline (1142.655 us; speedup 1.0000x reference)
//
#include <hip/hip_runtime.h>
#include <math.h>

// Problem constants (fixed by the reference)
constexpr int N_NODES = 50000;
constexpr int N_EDGES = 800000;
constexpr int DIM     = 128;
constexpr int NLAYERS = 3;
constexpr int NGRAPH  = 64;
constexpr int DOUT    = 10;
constexpr float EPS_BN  = 1e-5f;
constexpr float EPS_AGG = 1e-6f;

typedef __attribute__((ext_vector_type(8))) short   bf16x8;
typedef __attribute__((ext_vector_type(4))) float   floatx4;
typedef __attribute__((ext_vector_type(4))) unsigned short ushort4v;

__device__ inline unsigned short f2bf(float f) {
    union { float f; unsigned int u; } v; v.f = f;
    unsigned int u = v.u;
    return (unsigned short)((u + 0x7fffu + ((u >> 16) & 1u)) >> 16);  // RNE
}
__device__ inline float bf2f(unsigned short h) {
    union { unsigned int u; float f; } v; v.u = ((unsigned int)h) << 16;
    return v.f;
}

// ---------------- CSR build ----------------
__global__ void hist_kernel(const int* __restrict__ dst, int* __restrict__ cnt) {
    int e = blockIdx.x * 256 + threadIdx.x;
    if (e < N_EDGES) atomicAdd(&cnt[dst[e]], 1);
}

__global__ void scan1_kernel(const int* __restrict__ cnt, int* __restrict__ row_ptr,
                             int* __restrict__ partials) {
    __shared__ int s[256];
    int i = blockIdx.x * 256 + threadIdx.x;
    int v = (i < N_NODES) ? cnt[i] : 0;
    s[threadIdx.x] = v;
    __syncthreads();
    for (int off = 1; off < 256; off <<= 1) {
        int t = (threadIdx.x >= off) ? s[threadIdx.x - off] : 0;
        __syncthreads();
        s[threadIdx.x] += t;
        __syncthreads();
    }
    if (i < N_NODES) row_ptr[i] = s[threadIdx.x] - v;   // exclusive within block
    if (threadIdx.x == 255) partials[blockIdx.x] = s[255];
}

__global__ void scan2_kernel(int* partials, int nb) {
    __shared__ int s[256];
    int t = threadIdx.x;
    int v = (t < nb) ? partials[t] : 0;
    s[t] = v;
    __syncthreads();
    for (int off = 1; off < 256; off <<= 1) {
        int u = (t >= off) ? s[t - off] : 0;
        __syncthreads();
        s[t] += u;
        __syncthreads();
    }
    if (t < nb) partials[t] = s[t] - v;                 // exclusive block offsets
}

__global__ void scan3_kernel(int* row_ptr, const int* __restrict__ partials) {
    int i = blockIdx.x * 256 + threadIdx.x;
    if (i < N_NODES) row_ptr[i] += partials[blockIdx.x];
    if (blockIdx.x == 0 && threadIdx.x == 0) row_ptr[N_NODES] = N_EDGES;
}

__global__ void scatter_kernel(const int* __restrict__ src, const int* __restrict__ dst,
                               const int* __restrict__ row_ptr, int* __restrict__ cursor,
                               int* __restrict__ col_src) {
    int e = blockIdx.x * 256 + threadIdx.x;
    if (e < N_EDGES) {
        int d = dst[e];
        int pos = row_ptr[d] + atomicAdd(&cursor[d], 1);
        col_src[pos] = src[e];
    }
}

// ---------------- Weight convert+transpose: Wt[lk][c][d] = bf16(W[lk][d][c]) ----------------
__global__ void wconv_kernel(const float* __restrict__ W, unsigned short* __restrict__ Wt) {
    int idx = blockIdx.x * 256 + threadIdx.x;               // 196608 total
    int c = idx & 127, d = (idx >> 7) & 127, lk = idx >> 14;
    Wt[((size_t)lk * 128 + c) * 128 + d] = f2bf(W[idx]);
}

// ---------------- x init: fp32 master copy + bf16 shadow ----------------
__global__ __launch_bounds__(256) void xinit_kernel(const float* __restrict__ x_in,
                                                    float* __restrict__ x_cur,
                                                    unsigned short* __restrict__ xb) {
    int i4 = blockIdx.x * 256 + threadIdx.x;                // over N*DIM/4
    float4 v = *(const float4*)&x_in[(size_t)i4 * 4];
    *(float4*)&x_cur[(size_t)i4 * 4] = v;
    ushort4v b; b.x = f2bf(v.x); b.y = f2bf(v.y); b.z = f2bf(v.z); b.w = f2bf(v.w);
    *(ushort4v*)&xb[(size_t)i4 * 4] = b;
}

// ---------------- MFMA projection GEMM ----------------
// ksl=0 -> Axh (fp32), ksl=2 -> Dx (fp32),
// ksl=1 -> Bx as bf16 into lo16 of EB, ksl=3 -> Ex as bf16 into hi16 of EB.
// Block: 256 thr = 4 waves (2x2), tile 128(m) x 128(c), K=128 in 4 steps, no LDS.
// Block (0,0) additionally zero-inits the 8-copy BN accumulators for this layer.
__global__ __launch_bounds__(256) void gemm_mfma(const unsigned short* __restrict__ xb,
                                                 const unsigned short* __restrict__ Wt,
                                                 const float* __restrict__ bias,
                                                 float* __restrict__ Axh,
                                                 float* __restrict__ Dx,
                                                 unsigned int* __restrict__ EB,
                                                 float* __restrict__ bn8) {
    const int ksl = blockIdx.y;
    const int m0  = blockIdx.x * 128;
    const int tid = threadIdx.x;

    if (blockIdx.x == 0 && ksl == 0) {
#pragma unroll
        for (int c = 0; c < 8; c++) bn8[c * 256 + tid] = 0.f;
    }

    const int wave = tid >> 6, lane = tid & 63;
    const int wm = (wave >> 1) * 64, wc = (wave & 1) * 64;
    const int quad = lane >> 4, l16 = lane & 15;
    const unsigned short* Wk = Wt + (size_t)ksl * DIM * DIM;

    floatx4 acc[4][4];
#pragma unroll
    for (int i = 0; i < 4; i++)
#pragma unroll
        for (int j = 0; j < 4; j++) acc[i][j] = (floatx4)0.f;

#pragma unroll
    for (int ks = 0; ks < 4; ks++) {
        const int kk = ks * 32 + quad * 8;
        bf16x8 a[4], b[4];
#pragma unroll
        for (int i = 0; i < 4; i++) {
            int row = m0 + wm + i * 16 + l16;
            row = min(row, N_NODES - 1);
            a[i] = *(const bf16x8*)&xb[(size_t)row * DIM + kk];
        }
#pragma unroll
        for (int j = 0; j < 4; j++) {
            int col = wc + j * 16 + l16;
            b[j] = *(const bf16x8*)&Wk[(size_t)col * DIM + kk];
        }
#pragma unroll
        for (int i = 0; i < 4; i++)
#pragma unroll
            for (int j = 0; j < 4; j++)
                acc[i][j] = __builtin_amdgcn_mfma_f32_16x16x32_bf16(a[i], b[j], acc[i][j], 0, 0, 0);
    }

    float bv[4];
#pragma unroll
    for (int j = 0; j < 4; j++) bv[j] = bias[ksl * DIM + wc + j * 16 + l16];

    float* fdst = (ksl == 0) ? Axh : Dx;                    // valid for ksl 0/2
    unsigned short* ebp = (unsigned short*)EB;
    const int half = (ksl == 3) ? 1 : 0;                    // Ex -> hi16, Bx -> lo16

#pragma unroll
    for (int i = 0; i < 4; i++) {
#pragma unroll
        for (int r = 0; r < 4; r++) {
            int row = m0 + wm + i * 16 + quad * 4 + r;
            if (row >= N_NODES) continue;
            if ((ksl & 1) == 0) {
                float* op = fdst + (size_t)row * DIM;
#pragma unroll
                for (int j = 0; j < 4; j++)
                    op[wc + j * 16 + l16] = acc[i][j][r] + bv[j];
            } else {
                unsigned short* op = ebp + (size_t)row * DIM * 2 + half;
#pragma unroll
                for (int j = 0; j < 4; j++)
                    op[(wc + j * 16 + l16) * 2] = f2bf(acc[i][j][r] + bv[j]);
            }
        }
    }
}

// ---------------- Edge aggregation + fused BN stats ----------------
// 256 threads = 2 node-slots x 128 d-lanes; 8 nodes per slot -> 16 nodes/block.
// grid = N_NODES/16 = 3125 blocks (16x fewer WG launches than 1 node/block).
// Inner loop: fixed-shape rounds of 8 predicated gathers (no dependent tail).
// h overwrites Axh in place; per-thread BN partials reduced in LDS, then
// atomically added into one of 8 spread accumulator copies (bn8[8][2][128]).
__global__ __launch_bounds__(256) void agg_kernel(float* __restrict__ Axh,
                                                  const float* __restrict__ Dx,
                                                  const unsigned int* __restrict__ EB,
                                                  const int* __restrict__ row_ptr,
                                                  const int* __restrict__ col_src,
                                                  float* __restrict__ bn8) {
    const int slot = threadIdx.x >> 7;        // 0/1
    const int d    = threadIdx.x & 127;
    const int i0   = (blockIdx.x * 2 + slot) * 8;

    float s_acc = 0.f, q_acc = 0.f;

#pragma unroll 1
    for (int n = 0; n < 8; n++) {
        const int i = i0 + n;
        const float ax = Axh[(size_t)i * DIM + d];          // issue early, used at end
        const float dx = Dx[(size_t)i * DIM + d];
        const int e0 = row_ptr[i];
        const int e1 = row_ptr[i + 1];
        float num = 0.f, den = 0.f;
        const int nr = (e1 - e0 + 7) >> 3;
#pragma unroll 1
        for (int r = 0; r < nr; r++) {
            const int eb = e0 + r * 8;
            int idx[8];
#pragma unroll
            for (int k = 0; k < 8; k++) idx[k] = col_src[min(eb + k, e1 - 1)];
            unsigned int w[8];
#pragma unroll
            for (int k = 0; k < 8; k++) w[k] = EB[(size_t)idx[k] * DIM + d];
#pragma unroll
            for (int k = 0; k < 8; k++) {
                float ex = bf2f((unsigned short)(w[k] >> 16));
                float bx = bf2f((unsigned short)(w[k] & 0xffffu));
                float sg = 1.f / (1.f + __expf(-(dx + ex)));
                sg = (eb + k < e1) ? sg : 0.f;              // mask padded lanes of round
                num += sg * bx;
                den += sg;
            }
        }
        const float h = ax + num / (den + EPS_AGG);
        Axh[(size_t)i * DIM + d] = h;
        s_acc += h;
        q_acc += h * h;
    }

    __shared__ float ls[256], lq[256];
    ls[threadIdx.x] = s_acc; lq[threadIdx.x] = q_acc;
    __syncthreads();
    if (threadIdx.x < 128) {
        float* bp = bn8 + (blockIdx.x & 7) * 256;           // 8-way contention spread
        atomicAdd(&bp[d],       ls[threadIdx.x] + ls[threadIdx.x + 128]);
        atomicAdd(&bp[128 + d], lq[threadIdx.x] + lq[threadIdx.x + 128]);
    }
}

// ---------------- BN finalize + apply + ReLU + residual (fused) ----------------
// Each block reduces the 8 BN partial copies (8 KB, L2-hot) to scale/shift in LDS,
// then applies: x += relu(h*scale+shift); refresh fp32 master + bf16 shadow.
__global__ __launch_bounds__(256) void apply_kernel(const float* __restrict__ h,
                                                    const float* __restrict__ bn8,
                                                    const float* __restrict__ gamma,
                                                    const float* __restrict__ beta,
                                                    float* __restrict__ x,
                                                    unsigned short* __restrict__ xb) {
    __shared__ float ssc[128], ssh[128];
    const int t = threadIdx.x;
    if (t < 128) {
        float s = 0.f, q = 0.f;
#pragma unroll
        for (int c = 0; c < 8; c++) { s += bn8[c * 256 + t]; q += bn8[c * 256 + 128 + t]; }
        const float mu  = s * (1.f / N_NODES);
        const float var = q * (1.f / N_NODES) - mu * mu;
        const float sc  = gamma[t] * rsqrtf(var + EPS_BN);
        ssc[t] = sc;
        ssh[t] = beta[t] - mu * sc;
    }
    __syncthreads();

    int i4 = blockIdx.x * 256 + t;                // over N*DIM/4
    int d  = (i4 * 4) & 127;
    float4 hv = *(const float4*)&h[(size_t)i4 * 4];
    float4 xv = *(float4*)&x[(size_t)i4 * 4];
    xv.x += fmaxf(hv.x * ssc[d + 0] + ssh[d + 0], 0.f);
    xv.y += fmaxf(hv.y * ssc[d + 1] + ssh[d + 1], 0.f);
    xv.z += fmaxf(hv.z * ssc[d + 2] + ssh[d + 2], 0.f);
    xv.w += fmaxf(hv.w * ssc[d + 3] + ssh[d + 3], 0.f);
    *(float4*)&x[(size_t)i4 * 4] = xv;
    ushort4v b; b.x = f2bf(xv.x); b.y = f2bf(xv.y); b.z = f2bf(xv.z); b.w = f2bf(xv.w);
    *(ushort4v*)&xb[(size_t)i4 * 4] = b;
}

// ---------------- Mean pool by graph (batch_vec sorted) ----------------
__global__ __launch_bounds__(128) void pool_kernel(const float* __restrict__ x,
                                                   const int* __restrict__ batch,
                                                   float* __restrict__ pooled,
                                                   int* __restrict__ gcount) {
    int d = threadIdx.x;
    int r0 = blockIdx.x * 256;
    int r1 = min(r0 + 256, N_NODES);
    int curg = batch[r0];
    float acc = 0.f;
    int run = 0;
    for (int r = r0; r < r1; r++) {
        int g = batch[r];
        if (g != curg) {
            atomicAdd(&pooled[curg * DIM + d], acc);
            if (d == 0) atomicAdd(&gcount[curg], run);
            acc = 0.f; run = 0; curg = g;
        }
        acc += x[(size_t)r * DIM + d];
        run++;
    }
    atomicAdd(&pooled[curg * DIM + d], acc);
    if (d == 0) atomicAdd(&gcount[curg], run);
}

// ---------------- Head ----------------
__global__ __launch_bounds__(128) void head_kernel(const float* __restrict__ pooled,
                                                   const int* __restrict__ gcount,
                                                   const float* __restrict__ w1,
                                                   const float* __restrict__ b1,
                                                   const float* __restrict__ w2,
                                                   const float* __restrict__ b2,
                                                   float* __restrict__ out) {
    __shared__ float sp[128], sh[128];
    int g = blockIdx.x, d = threadIdx.x;
    float c = (float)max(gcount[g], 1);
    sp[d] = pooled[g * DIM + d] / c;
    __syncthreads();
    float acc = b1[d];
    for (int dd = 0; dd < DIM; dd++) acc += sp[dd] * w1[dd * DIM + d];
    sh[d] = fmaxf(acc, 0.f);
    __syncthreads();
    if (d < DOUT) {
        float o = b2[d];
        for (int dd = 0; dd < DIM; dd++) o += sh[dd] * w2[dd * DOUT + d];
        out[g * DOUT + d] = o;
    }
}

extern "C" void kernel_launch(void* const* d_in, const int* in_sizes, int n_in,
                              void* d_out, int out_size, void* d_ws, size_t ws_size,
                              hipStream_t stream) {
    const float* x_in  = (const float*)d_in[0];
    // d_in[1] = edge_attr — UNUSED by the forward pass; fallback scratch.
    const int*   eidx  = (const int*)d_in[2];
    const int*   batch = (const int*)d_in[3];
    const float* lin_w = (const float*)d_in[4];
    const float* lin_b = (const float*)d_in[5];
    const float* gamma = (const float*)d_in[6];
    const float* beta  = (const float*)d_in[7];
    const float* w1    = (const float*)d_in[8];
    const float* b1    = (const float*)d_in[9];
    const float* w2    = (const float*)d_in[10];
    const float* b2    = (const float*)d_in[11];
    float* out = (float*)d_out;

    const int* src = eidx;             // edge_index[0]
    const int* dst = eidx + N_EDGES;   // edge_index[1]

    // Workspace layout
    auto al = [](size_t v) { return (v + 255) & ~(size_t)255; };
    size_t off = 0;
    size_t o_xcur = off; off = al(off + (size_t)N_NODES * DIM * 4);
    size_t o_xb   = off; off = al(off + (size_t)N_NODES * DIM * 2);
    size_t o_wt   = off; off = al(off + (size_t)NLAYERS * 4 * DIM * DIM * 2);
    size_t o_axh  = off; off = al(off + (size_t)N_NODES * DIM * 4);
    size_t o_dx   = off; off = al(off + (size_t)N_NODES * DIM * 4);
    size_t o_eb   = off; off = al(off + (size_t)N_NODES * DIM * 4);
    size_t o_rp   = off; off = al(off + (size_t)(N_NODES + 1) * 4);
    size_t o_cs   = off; off = al(off + (size_t)N_EDGES * 4);
    size_t o_cnt  = off; off = al(off + (size_t)N_NODES * 4);
    size_t o_part = off; off = al(off + 256 * 4);
    size_t o_bn   = off; off = al(off + 2048 * 4);          // bn8: [8][2][128] floats
    size_t o_pool = off; off = al(off + (size_t)NGRAPH * DIM * 4);
    size_t o_gc   = off; off = al(off + (size_t)NGRAPH * 4);
    size_t total  = off;

    char* base = (ws_size >= total) ? (char*)d_ws : (char*)d_in[1];

    float*          x_cur    = (float*)(base + o_xcur);
    unsigned short* xb       = (unsigned short*)(base + o_xb);
    unsigned short* Wt       = (unsigned short*)(base + o_wt);
    float*          Axh      = (float*)(base + o_axh);
    float*          Dx       = (float*)(base + o_dx);
    unsigned int*   EB       = (unsigned int*)(base + o_eb);
    int*            row_ptr  = (int*)  (base + o_rp);
    int*            col_src  = (int*)  (base + o_cs);
    int*            cnt      = (int*)  (base + o_cnt);
    int*            partials = (int*)  (base + o_part);
    float*          bn8      = (float*)(base + o_bn);
    float*          pooled   = (float*)(base + o_pool);
    int*            gcount   = (int*)  (base + o_gc);

    const int nbN = (N_NODES + 255) / 256;   // 196
    const int nbE = (N_EDGES + 255) / 256;   // 3125
    const int nb4 = (N_NODES * DIM / 4) / 256; // 6250
    const int nbAgg = N_NODES / 16;          // 3125 (16 nodes per block, exact)

    // x master + bf16 shadow; weight conversion
    xinit_kernel<<<nb4, 256, 0, stream>>>(x_in, x_cur, xb);
    wconv_kernel<<<(NLAYERS * 4 * DIM * DIM) / 256, 256, 0, stream>>>(lin_w, Wt);

    // Build CSR by dst (edge_index is constant across layers)
    hipMemsetAsync(cnt, 0, (size_t)N_NODES * 4, stream);
    hist_kernel<<<nbE, 256, 0, stream>>>(dst, cnt);
    scan1_kernel<<<nbN, 256, 0, stream>>>(cnt, row_ptr, partials);
    scan2_kernel<<<1, 256, 0, stream>>>(partials, nbN);
    scan3_kernel<<<nbN, 256, 0, stream>>>(row_ptr, partials);
    hipMemsetAsync(cnt, 0, (size_t)N_NODES * 4, stream);
    scatter_kernel<<<nbE, 256, 0, stream>>>(src, dst, row_ptr, cnt, col_src);

    for (int l = 0; l < NLAYERS; l++) {
        gemm_mfma<<<dim3((N_NODES + 127) / 128, 4), 256, 0, stream>>>(
            xb, Wt + (size_t)l * 4 * DIM * DIM, lin_b + (size_t)l * 4 * DIM, Axh, Dx, EB, bn8);
        agg_kernel<<<nbAgg, 256, 0, stream>>>(Axh, Dx, EB, row_ptr, col_src, bn8);
        apply_kernel<<<nb4, 256, 0, stream>>>(Axh, bn8, gamma + (size_t)l * DIM,
                                              beta + (size_t)l * DIM, x_cur, xb);
    }

    hipMemsetAsync(pooled, 0, (size_t)NGRAPH * DIM * 4, stream);
    hipMemsetAsync(gcount, 0, (size_t)NGRAPH * 4, stream);
    pool_kernel<<<nbN, 128, 0, stream>>>(x_cur, batch, pooled, gcount);
    head_kernel<<<NGRAPH, 128, 0, stream>>>(pooled, gcount, w1, b1, w2, b2, out);
}

// Round 3
// 1137.696 us; speedup vs baseline: 1.0044x; 1.0044x over previous
//
#include <hip/hip_runtime.h>
#include <math.h>

// Problem constants (fixed by the reference)
constexpr int N_NODES = 50000;
constexpr int N_EDGES = 800000;
constexpr int DIM     = 128;
constexpr int NLAYERS = 3;
constexpr int NGRAPH  = 64;
constexpr int DOUT    = 10;
constexpr float EPS_BN  = 1e-5f;
constexpr float EPS_AGG = 1e-6f;

typedef __attribute__((ext_vector_type(8))) short   bf16x8;
typedef __attribute__((ext_vector_type(4))) float   floatx4;
typedef __attribute__((ext_vector_type(4))) unsigned short ushort4v;
typedef __attribute__((ext_vector_type(2))) unsigned int uint2v;
typedef __attribute__((ext_vector_type(2))) float float2v;

__device__ inline unsigned short f2bf(float f) {
    union { float f; unsigned int u; } v; v.f = f;
    unsigned int u = v.u;
    return (unsigned short)((u + 0x7fffu + ((u >> 16) & 1u)) >> 16);  // RNE
}
__device__ inline float bf2f(unsigned short h) {
    union { unsigned int u; float f; } v; v.u = ((unsigned int)h) << 16;
    return v.f;
}

// ---------------- CSR build ----------------
__global__ void hist_kernel(const int* __restrict__ dst, int* __restrict__ cnt) {
    int e = blockIdx.x * 256 + threadIdx.x;
    if (e < N_EDGES) atomicAdd(&cnt[dst[e]], 1);
}

__global__ void scan1_kernel(const int* __restrict__ cnt, int* __restrict__ row_ptr,
                             int* __restrict__ partials) {
    __shared__ int s[256];
    int i = blockIdx.x * 256 + threadIdx.x;
    int v = (i < N_NODES) ? cnt[i] : 0;
    s[threadIdx.x] = v;
    __syncthreads();
    for (int off = 1; off < 256; off <<= 1) {
        int t = (threadIdx.x >= off) ? s[threadIdx.x - off] : 0;
        __syncthreads();
        s[threadIdx.x] += t;
        __syncthreads();
    }
    if (i < N_NODES) row_ptr[i] = s[threadIdx.x] - v;   // exclusive within block
    if (threadIdx.x == 255) partials[blockIdx.x] = s[255];
}

__global__ void scan2_kernel(int* partials, int nb) {
    __shared__ int s[256];
    int t = threadIdx.x;
    int v = (t < nb) ? partials[t] : 0;
    s[t] = v;
    __syncthreads();
    for (int off = 1; off < 256; off <<= 1) {
        int u = (t >= off) ? s[t - off] : 0;
        __syncthreads();
        s[t] += u;
        __syncthreads();
    }
    if (t < nb) partials[t] = s[t] - v;                 // exclusive block offsets
}

__global__ void scan3_kernel(int* row_ptr, const int* __restrict__ partials) {
    int i = blockIdx.x * 256 + threadIdx.x;
    if (i < N_NODES) row_ptr[i] += partials[blockIdx.x];
    if (blockIdx.x == 0 && threadIdx.x == 0) row_ptr[N_NODES] = N_EDGES;
}

__global__ void scatter_kernel(const int* __restrict__ src, const int* __restrict__ dst,
                               const int* __restrict__ row_ptr, int* __restrict__ cursor,
                               int* __restrict__ col_src) {
    int e = blockIdx.x * 256 + threadIdx.x;
    if (e < N_EDGES) {
        int d = dst[e];
        int pos = row_ptr[d] + atomicAdd(&cursor[d], 1);
        col_src[pos] = src[e];
    }
}

// ---------------- Weight convert+transpose: Wt[lk][c][d] = bf16(W[lk][d][c]) ----------------
__global__ void wconv_kernel(const float* __restrict__ W, unsigned short* __restrict__ Wt) {
    int idx = blockIdx.x * 256 + threadIdx.x;               // 196608 total
    int c = idx & 127, d = (idx >> 7) & 127, lk = idx >> 14;
    Wt[((size_t)lk * 128 + c) * 128 + d] = f2bf(W[idx]);
}

// ---------------- x init: fp32 master copy + bf16 shadow ----------------
__global__ __launch_bounds__(256) void xinit_kernel(const float* __restrict__ x_in,
                                                    float* __restrict__ x_cur,
                                                    unsigned short* __restrict__ xb) {
    int i4 = blockIdx.x * 256 + threadIdx.x;                // over N*DIM/4
    float4 v = *(const float4*)&x_in[(size_t)i4 * 4];
    *(float4*)&x_cur[(size_t)i4 * 4] = v;
    ushort4v b; b.x = f2bf(v.x); b.y = f2bf(v.y); b.z = f2bf(v.z); b.w = f2bf(v.w);
    *(ushort4v*)&xb[(size_t)i4 * 4] = b;
}

// ---------------- MFMA projection GEMM ----------------
// ksl=0 -> Axh (fp32), ksl=2 -> Dx (fp32),
// ksl=1 -> Bx as bf16 into lo16 of EB, ksl=3 -> Ex as bf16 into hi16 of EB.
// Block: 256 thr = 4 waves (2x2), tile 128(m) x 128(c), K=128 in 4 steps, no LDS.
// Block (0,0) additionally zero-inits the 8-copy BN accumulators for this layer.
__global__ __launch_bounds__(256) void gemm_mfma(const unsigned short* __restrict__ xb,
                                                 const unsigned short* __restrict__ Wt,
                                                 const float* __restrict__ bias,
                                                 float* __restrict__ Axh,
                                                 float* __restrict__ Dx,
                                                 unsigned int* __restrict__ EB,
                                                 float* __restrict__ bn8) {
    const int ksl = blockIdx.y;
    const int m0  = blockIdx.x * 128;
    const int tid = threadIdx.x;

    if (blockIdx.x == 0 && ksl == 0) {
#pragma unroll
        for (int c = 0; c < 8; c++) bn8[c * 256 + tid] = 0.f;
    }

    const int wave = tid >> 6, lane = tid & 63;
    const int wm = (wave >> 1) * 64, wc = (wave & 1) * 64;
    const int quad = lane >> 4, l16 = lane & 15;
    const unsigned short* Wk = Wt + (size_t)ksl * DIM * DIM;

    floatx4 acc[4][4];
#pragma unroll
    for (int i = 0; i < 4; i++)
#pragma unroll
        for (int j = 0; j < 4; j++) acc[i][j] = (floatx4)0.f;

#pragma unroll
    for (int ks = 0; ks < 4; ks++) {
        const int kk = ks * 32 + quad * 8;
        bf16x8 a[4], b[4];
#pragma unroll
        for (int i = 0; i < 4; i++) {
            int row = m0 + wm + i * 16 + l16;
            row = min(row, N_NODES - 1);
            a[i] = *(const bf16x8*)&xb[(size_t)row * DIM + kk];
        }
#pragma unroll
        for (int j = 0; j < 4; j++) {
            int col = wc + j * 16 + l16;
            b[j] = *(const bf16x8*)&Wk[(size_t)col * DIM + kk];
        }
#pragma unroll
        for (int i = 0; i < 4; i++)
#pragma unroll
            for (int j = 0; j < 4; j++)
                acc[i][j] = __builtin_amdgcn_mfma_f32_16x16x32_bf16(a[i], b[j], acc[i][j], 0, 0, 0);
    }

    float bv[4];
#pragma unroll
    for (int j = 0; j < 4; j++) bv[j] = bias[ksl * DIM + wc + j * 16 + l16];

    float* fdst = (ksl == 0) ? Axh : Dx;                    // valid for ksl 0/2
    unsigned short* ebp = (unsigned short*)EB;
    const int half = (ksl == 3) ? 1 : 0;                    // Ex -> hi16, Bx -> lo16

#pragma unroll
    for (int i = 0; i < 4; i++) {
#pragma unroll
        for (int r = 0; r < 4; r++) {
            int row = m0 + wm + i * 16 + quad * 4 + r;
            if (row >= N_NODES) continue;
            if ((ksl & 1) == 0) {
                float* op = fdst + (size_t)row * DIM;
#pragma unroll
                for (int j = 0; j < 4; j++)
                    op[wc + j * 16 + l16] = acc[i][j][r] + bv[j];
            } else {
                unsigned short* op = ebp + (size_t)row * DIM * 2 + half;
#pragma unroll
                for (int j = 0; j < 4; j++)
                    op[(wc + j * 16 + l16) * 2] = f2bf(acc[i][j][r] + bv[j]);
            }
        }
    }
}

// ---------------- Edge aggregation + fused BN stats ----------------
// One wave = 8 nodes, 64 lanes x 2 dims (uint2/float2 per lane -> full 512B row
// per single wave memory request). Block = 4 waves = 32 nodes; grid = 1563.
// Rounds of 8 independent gathers; compiler free to pipeline across rounds.
__global__ __launch_bounds__(256) void agg_kernel(float* __restrict__ Axh,
                                                  const float* __restrict__ Dx,
                                                  const unsigned int* __restrict__ EB,
                                                  const int* __restrict__ row_ptr,
                                                  const int* __restrict__ col_src,
                                                  float* __restrict__ bn8) {
    const int wave = threadIdx.x >> 6;        // 0..3
    const int lane = threadIdx.x & 63;
    const int d0   = lane * 2;                // dims d0, d0+1
    const int i0   = (blockIdx.x * 4 + wave) * 8;

    float s0 = 0.f, q0 = 0.f, s1 = 0.f, q1 = 0.f;

    for (int n = 0; n < 8; n++) {
        const int i = i0 + n;
        const bool valid = (i < N_NODES);
        const int ic = valid ? i : N_NODES - 1;

        const float2v ax = *(const float2v*)&Axh[(size_t)ic * DIM + d0];
        const float2v dx = *(const float2v*)&Dx[(size_t)ic * DIM + d0];
        const int e0 = row_ptr[ic];
        const int e1 = row_ptr[ic + 1];

        float num0 = 0.f, den0 = 0.f, num1 = 0.f, den1 = 0.f;
        const int nr = (e1 - e0 + 7) >> 3;
        for (int r = 0; r < nr; r++) {
            const int eb = e0 + r * 8;
            int idx[8];
#pragma unroll
            for (int k = 0; k < 8; k++) idx[k] = col_src[min(eb + k, e1 - 1)];
            uint2v w[8];
#pragma unroll
            for (int k = 0; k < 8; k++)
                w[k] = *(const uint2v*)&EB[(size_t)idx[k] * DIM + d0];
#pragma unroll
            for (int k = 0; k < 8; k++) {
                const float ex0 = bf2f((unsigned short)(w[k].x >> 16));
                const float bx0 = bf2f((unsigned short)(w[k].x & 0xffffu));
                const float ex1 = bf2f((unsigned short)(w[k].y >> 16));
                const float bx1 = bf2f((unsigned short)(w[k].y & 0xffffu));
                float sg0 = 1.f / (1.f + __expf(-(dx.x + ex0)));
                float sg1 = 1.f / (1.f + __expf(-(dx.y + ex1)));
                const bool live = (eb + k < e1);
                sg0 = live ? sg0 : 0.f;
                sg1 = live ? sg1 : 0.f;
                num0 += sg0 * bx0; den0 += sg0;
                num1 += sg1 * bx1; den1 += sg1;
            }
        }
        const float h0 = ax.x + num0 / (den0 + EPS_AGG);
        const float h1 = ax.y + num1 / (den1 + EPS_AGG);
        if (valid) {
            float2v hv; hv.x = h0; hv.y = h1;
            *(float2v*)&Axh[(size_t)ic * DIM + d0] = hv;
            s0 += h0; q0 += h0 * h0;
            s1 += h1; q1 += h1 * h1;
        }
    }

    // BN partial reduce across the 4 waves, then 8-way-spread global atomics.
    __shared__ float rs[4 * 128], rq[4 * 128];
    rs[wave * 128 + d0]     = s0;  rq[wave * 128 + d0]     = q0;
    rs[wave * 128 + d0 + 1] = s1;  rq[wave * 128 + d0 + 1] = q1;
    __syncthreads();
    if (threadIdx.x < 128) {
        const int d = threadIdx.x;
        const float s = rs[d] + rs[128 + d] + rs[256 + d] + rs[384 + d];
        const float q = rq[d] + rq[128 + d] + rq[256 + d] + rq[384 + d];
        float* bp = bn8 + (blockIdx.x & 7) * 256;
        atomicAdd(&bp[d], s);
        atomicAdd(&bp[128 + d], q);
    }
}

// ---------------- BN finalize + apply + ReLU + residual (fused) ----------------
// Each block reduces the 8 BN partial copies (8 KB, L2-hot) to scale/shift in LDS,
// then applies: x += relu(h*scale+shift); refresh fp32 master + bf16 shadow.
__global__ __launch_bounds__(256) void apply_kernel(const float* __restrict__ h,
                                                    const float* __restrict__ bn8,
                                                    const float* __restrict__ gamma,
                                                    const float* __restrict__ beta,
                                                    float* __restrict__ x,
                                                    unsigned short* __restrict__ xb) {
    __shared__ float ssc[128], ssh[128];
    const int t = threadIdx.x;
    if (t < 128) {
        float s = 0.f, q = 0.f;
#pragma unroll
        for (int c = 0; c < 8; c++) { s += bn8[c * 256 + t]; q += bn8[c * 256 + 128 + t]; }
        const float mu  = s * (1.f / N_NODES);
        const float var = q * (1.f / N_NODES) - mu * mu;
        const float sc  = gamma[t] * rsqrtf(var + EPS_BN);
        ssc[t] = sc;
        ssh[t] = beta[t] - mu * sc;
    }
    __syncthreads();

    int i4 = blockIdx.x * 256 + t;                // over N*DIM/4
    int d  = (i4 * 4) & 127;
    float4 hv = *(const float4*)&h[(size_t)i4 * 4];
    float4 xv = *(float4*)&x[(size_t)i4 * 4];
    xv.x += fmaxf(hv.x * ssc[d + 0] + ssh[d + 0], 0.f);
    xv.y += fmaxf(hv.y * ssc[d + 1] + ssh[d + 1], 0.f);
    xv.z += fmaxf(hv.z * ssc[d + 2] + ssh[d + 2], 0.f);
    xv.w += fmaxf(hv.w * ssc[d + 3] + ssh[d + 3], 0.f);
    *(float4*)&x[(size_t)i4 * 4] = xv;
    ushort4v b; b.x = f2bf(xv.x); b.y = f2bf(xv.y); b.z = f2bf(xv.z); b.w = f2bf(xv.w);
    *(ushort4v*)&xb[(size_t)i4 * 4] = b;
}

// ---------------- Mean pool by graph (batch_vec sorted) ----------------
__global__ __launch_bounds__(128) void pool_kernel(const float* __restrict__ x,
                                                   const int* __restrict__ batch,
                                                   float* __restrict__ pooled,
                                                   int* __restrict__ gcount) {
    int d = threadIdx.x;
    int r0 = blockIdx.x * 256;
    int r1 = min(r0 + 256, N_NODES);
    int curg = batch[r0];
    float acc = 0.f;
    int run = 0;
    for (int r = r0; r < r1; r++) {
        int g = batch[r];
        if (g != curg) {
            atomicAdd(&pooled[curg * DIM + d], acc);
            if (d == 0) atomicAdd(&gcount[curg], run);
            acc = 0.f; run = 0; curg = g;
        }
        acc += x[(size_t)r * DIM + d];
        run++;
    }
    atomicAdd(&pooled[curg * DIM + d], acc);
    if (d == 0) atomicAdd(&gcount[curg], run);
}

// ---------------- Head ----------------
__global__ __launch_bounds__(128) void head_kernel(const float* __restrict__ pooled,
                                                   const int* __restrict__ gcount,
                                                   const float* __restrict__ w1,
                                                   const float* __restrict__ b1,
                                                   const float* __restrict__ w2,
                                                   const float* __restrict__ b2,
                                                   float* __restrict__ out) {
    __shared__ float sp[128], sh[128];
    int g = blockIdx.x, d = threadIdx.x;
    float c = (float)max(gcount[g], 1);
    sp[d] = pooled[g * DIM + d] / c;
    __syncthreads();
    float acc = b1[d];
    for (int dd = 0; dd < DIM; dd++) acc += sp[dd] * w1[dd * DIM + d];
    sh[d] = fmaxf(acc, 0.f);
    __syncthreads();
    if (d < DOUT) {
        float o = b2[d];
        for (int dd = 0; dd < DIM; dd++) o += sh[dd] * w2[dd * DOUT + d];
        out[g * DOUT + d] = o;
    }
}

extern "C" void kernel_launch(void* const* d_in, const int* in_sizes, int n_in,
                              void* d_out, int out_size, void* d_ws, size_t ws_size,
                              hipStream_t stream) {
    const float* x_in  = (const float*)d_in[0];
    // d_in[1] = edge_attr — UNUSED by the forward pass; fallback scratch.
    const int*   eidx  = (const int*)d_in[2];
    const int*   batch = (const int*)d_in[3];
    const float* lin_w = (const float*)d_in[4];
    const float* lin_b = (const float*)d_in[5];
    const float* gamma = (const float*)d_in[6];
    const float* beta  = (const float*)d_in[7];
    const float* w1    = (const float*)d_in[8];
    const float* b1    = (const float*)d_in[9];
    const float* w2    = (const float*)d_in[10];
    const float* b2    = (const float*)d_in[11];
    float* out = (float*)d_out;

    const int* src = eidx;             // edge_index[0]
    const int* dst = eidx + N_EDGES;   // edge_index[1]

    // Workspace layout
    auto al = [](size_t v) { return (v + 255) & ~(size_t)255; };
    size_t off = 0;
    size_t o_xcur = off; off = al(off + (size_t)N_NODES * DIM * 4);
    size_t o_xb   = off; off = al(off + (size_t)N_NODES * DIM * 2);
    size_t o_wt   = off; off = al(off + (size_t)NLAYERS * 4 * DIM * DIM * 2);
    size_t o_axh  = off; off = al(off + (size_t)N_NODES * DIM * 4);
    size_t o_dx   = off; off = al(off + (size_t)N_NODES * DIM * 4);
    size_t o_eb   = off; off = al(off + (size_t)N_NODES * DIM * 4);
    size_t o_rp   = off; off = al(off + (size_t)(N_NODES + 1) * 4);
    size_t o_cs   = off; off = al(off + (size_t)N_EDGES * 4);
    size_t o_cnt  = off; off = al(off + (size_t)N_NODES * 4);
    size_t o_part = off; off = al(off + 256 * 4);
    size_t o_bn   = off; off = al(off + 2048 * 4);          // bn8: [8][2][128] floats
    size_t o_pool = off; off = al(off + (size_t)NGRAPH * DIM * 4);
    size_t o_gc   = off; off = al(off + (size_t)NGRAPH * 4);
    size_t total  = off;

    char* base = (ws_size >= total) ? (char*)d_ws : (char*)d_in[1];

    float*          x_cur    = (float*)(base + o_xcur);
    unsigned short* xb       = (unsigned short*)(base + o_xb);
    unsigned short* Wt       = (unsigned short*)(base + o_wt);
    float*          Axh      = (float*)(base + o_axh);
    float*          Dx       = (float*)(base + o_dx);
    unsigned int*   EB       = (unsigned int*)(base + o_eb);
    int*            row_ptr  = (int*)  (base + o_rp);
    int*            col_src  = (int*)  (base + o_cs);
    int*            cnt      = (int*)  (base + o_cnt);
    int*            partials = (int*)  (base + o_part);
    float*          bn8      = (float*)(base + o_bn);
    float*          pooled   = (float*)(base + o_pool);
    int*            gcount   = (int*)  (base + o_gc);

    const int nbN = (N_NODES + 255) / 256;   // 196
    const int nbE = (N_EDGES + 255) / 256;   // 3125
    const int nb4 = (N_NODES * DIM / 4) / 256; // 6250
    const int nbAgg = (N_NODES + 31) / 32;   // 1563 (32 nodes per block)

    // x master + bf16 shadow; weight conversion
    xinit_kernel<<<nb4, 256, 0, stream>>>(x_in, x_cur, xb);
    wconv_kernel<<<(NLAYERS * 4 * DIM * DIM) / 256, 256, 0, stream>>>(lin_w, Wt);

    // Build CSR by dst (edge_index is constant across layers)
    hipMemsetAsync(cnt, 0, (size_t)N_NODES * 4, stream);
    hist_kernel<<<nbE, 256, 0, stream>>>(dst, cnt);
    scan1_kernel<<<nbN, 256, 0, stream>>>(cnt, row_ptr, partials);
    scan2_kernel<<<1, 256, 0, stream>>>(partials, nbN);
    scan3_kernel<<<nbN, 256, 0, stream>>>(row_ptr, partials);
    hipMemsetAsync(cnt, 0, (size_t)N_NODES * 4, stream);
    scatter_kernel<<<nbE, 256, 0, stream>>>(src, dst, row_ptr, cnt, col_src);

    for (int l = 0; l < NLAYERS; l++) {
        gemm_mfma<<<dim3((N_NODES + 127) / 128, 4), 256, 0, stream>>>(
            xb, Wt + (size_t)l * 4 * DIM * DIM, lin_b + (size_t)l * 4 * DIM, Axh, Dx, EB, bn8);
        agg_kernel<<<nbAgg, 256, 0, stream>>>(Axh, Dx, EB, row_ptr, col_src, bn8);
        apply_kernel<<<nb4, 256, 0, stream>>>(Axh, bn8, gamma + (size_t)l * DIM,
                                              beta + (size_t)l * DIM, x_cur, xb);
    }

    hipMemsetAsync(pooled, 0, (size_t)NGRAPH * DIM * 4, stream);
    hipMemsetAsync(gcount, 0, (size_t)NGRAPH * 4, stream);
    pool_kernel<<<nbN, 128, 0, stream>>>(x_cur, batch, pooled, gcount);
    head_kernel<<<NGRAPH, 128, 0, stream>>>(pooled, gcount, w1, b1, w2, b2, out);
}